// Round 1
// baseline (241.612 us; speedup 1.0000x reference)
//
#include <hip/hip_runtime.h>
#include <math.h>

#define TPB  256
#define TILE 512     // tokens per block; wave owns 128 (2/thread)

typedef float v4f __attribute__((ext_vector_type(4)));
typedef float v2f __attribute__((ext_vector_type(2)));

// Single fused kernel: R8 structure (zero barriers, coalesced NT loads,
// wave-private LDS transpose, NT stores) + wave-cooperative lower_bound
// on pu (replaces the boundary_kernel dispatch + its graph dependency).
__global__ __launch_bounds__(TPB) void verblizer_fused_kernel(
    const v4f*  __restrict__ x4,     // [S*5] float4 view of x[1,S,20]
    const v2f*  __restrict__ h2,     // [S]
    const float* __restrict__ W,     // [20,2,2]
    const float* __restrict__ b,     // [20,2]
    const int*   __restrict__ pu,    // [P] sorted unique
    v2f*         __restrict__ y,     // out1 [S]
    v2f*         __restrict__ y2,    // out2 [S]
    int S, int P)
{
    __shared__ uint2 scratch[(TPB / 64) * 640];  // wave-private, 20 KB/block

    const int t    = threadIdx.x;
    const int lane = t & 63;
    const int w    = t >> 6;
    const int B0   = min((int)blockIdx.x * TILE, S - TILE);  // full blocks only
    // overlapping blocks write identical values -> benign. B0 is 64-aligned.

    const int base = B0 + 128 * w;         // wave owns [base, base+128)
    const int s0   = base + lane;
    const int s1   = base + 64 + lane;

    // ---- issue streaming loads first (keep memory pipe busy) ----
    v4f xv[10];
    const v4f* xp = x4 + (size_t)base * 5;      // 640 contiguous float4s
#pragma unroll
    for (int j = 0; j < 10; ++j)
        xv[j] = __builtin_nontemporal_load(xp + 64 * j + lane);   // coalesced, nt

    const v2f h0 = __builtin_nontemporal_load(h2 + s0);
    const v2f h1 = __builtin_nontemporal_load(h2 + s1);

    // ---- per-chunk candidates -> wave-private LDS (no barrier) ----
    // (placed before the search so this VALU work fills the probe-latency
    //  shadows; compiler interleaves freely)
    uint2* sw = scratch + w * 640;
#pragma unroll
    for (int j = 0; j < 10; ++j) {
        v4f v = xv[j];
        float best = v.x; int bi = 0;
        if (v.y > best) { best = v.y; bi = 1; }
        if (v.z > best) { best = v.z; bi = 2; }
        if (v.w > best) { best = v.w; bi = 3; }
        const int flat = 64 * j + lane;     // chunk index in wave's 128-token span
        const int c    = flat % 5;          // chunk class within its token
        sw[flat] = make_uint2(__float_as_uint(best), (unsigned)(4 * c + bi));
    }

    // ---- wave-cooperative lower_bound(pu, base) -> r0 ----
    // Invariant: answer in [lo, lo+n]. 3 partition rounds (1e6 -> 15626 ->
    // 246 -> 5) + 1 count round. Round-1 probes are identical across all
    // waves -> L2-hot; pu is 4 MB total.
    int lo = 0, n = P;
    while (n > 64) {
        const int step = (n + 63) >> 6;                    // ceil(n/64)
        const int idx  = lo + lane * step;
        const int v    = (idx < P) ? pu[idx] : 0x7fffffff;
        const int c    = __popcll(__ballot(v < base));     // prefix-true count
        if (c > 0) lo += (c - 1) * step;
        n = step + 1;
    }
    {
        const int idx = lo + lane;
        const int v   = (lane < n && idx < P) ? pu[idx] : 0x7fffffff;
        lo += __popcll(__ballot(v < base));
    }
    const int r0 = lo;                      // == lower_bound(pu, base)

    // ---- window membership from two coalesced pu loads ----
    const int  i0  = r0 + lane;
    const int  i1  = r0 + 64 + lane;
    const int  q0  = pu[min(i0, P - 1)];    // pu[r0 .. r0+63]
    const int  q1  = pu[min(i1, P - 1)];    // pu[r0+64 .. r0+127]
    const bool ok0 = i0 < P;
    const bool ok1 = i1 < P;

    // window A = pu values in [base, base+64): all inside q0 (<=64 of them)
    const int nA = __popcll(__ballot(ok0 && q0 < base + 64));
    const int r1 = r0 + nA;                 // == lower_bound(pu, base+64)
    // window B = pu values in [base+64, base+128): inside q0 ∪ q1
    const int nB = __popcll(__ballot(ok0 && q0 >= base + 64 && q0 < base + 128))
                 + __popcll(__ballot(ok1 && q1 < base + 128)); // q1 >= base+64 implied
    // pB[lane] = pu[r1 + lane] for lane < nB, gathered from q0/q1 in-register
    const int ssel = nA + lane;             // 0..127
    const int pBa  = __shfl(q0, ssel & 63, 64);
    const int pBb  = __shfl(q1, ssel & 63, 64);
    const int pB   = (ssel < 64) ? pBa : pBb;
    const int pA   = q0;

    // ---- two wave-window membership masks (register-only butterfly OR) ----
    unsigned long long mA = (lane < nA) ? (1ull << ((unsigned)(pA - base) & 63)) : 0ull;
    unsigned long long mB = (lane < nB) ? (1ull << ((unsigned)(pB - base - 64) & 63)) : 0ull;
#pragma unroll
    for (int d = 1; d < 64; d <<= 1) {
        mA |= __shfl_xor(mA, d, 64);
        mB |= __shfl_xor(mB, d, 64);
    }
    const unsigned long long lt = (1ull << lane) - 1ull;
    const int  rankA = r0 + __popcll(mA & lt);
    const int  rankB = r1 + __popcll(mB & lt);
    const bool fA    = (mA >> lane) & 1;
    const bool fB    = (mB >> lane) & 1;

    // ---- per-token epilogue x2 ----
#pragma unroll
    for (int half = 0; half < 2; ++half) {
        const int   tl   = half ? (64 + lane) : lane;
        const v2f   hv   = half ? h1 : h0;
        const int   s    = half ? s1 : s0;
        const bool  f    = half ? fB : fA;
        const int   rnk  = half ? rankB : rankA;

        float best = -INFINITY; int bi = 0;
#pragma unroll
        for (int c = 0; c < 5; ++c) {
            uint2 p = sw[5 * tl + c];
            float v = __uint_as_float(p.x);
            if (v > best) { best = v; bi = (int)p.y; }
        }

        const float4 wv = *(const float4*)(W + bi * 4);  // L1-resident
        const float2 bv = *(const float2*)(b + bi * 2);
        float y0 = fmaf(hv.x, wv.x, fmaf(hv.y, wv.y, bv.x));
        float y1 = fmaf(hv.x, wv.z, fmaf(hv.y, wv.w, bv.y));
        float mx = fmaxf(y0, y1);
        float e0 = __expf(y0 - mx);
        float e1 = __expf(y1 - mx);
        float inv = 1.0f / (e0 + e1);
        v2f yo = { e0 * inv, e1 * inv };

        __builtin_nontemporal_store(yo, y + s);
        const int dst = f ? rnk : (P + s - rnk);
        __builtin_nontemporal_store(yo, y2 + dst);
    }
}

extern "C" void kernel_launch(void* const* d_in, const int* in_sizes, int n_in,
                              void* d_out, int out_size, void* d_ws, size_t ws_size,
                              hipStream_t stream) {
    const float* x  = (const float*)d_in[0];   // [1,S,20]
    const float* h  = (const float*)d_in[1];   // [S,2]
    const float* W  = (const float*)d_in[2];   // [20,2,2]
    const float* b  = (const float*)d_in[3];   // [20,2]
    const int*   pu = (const int*)d_in[4];     // [P]

    const int S  = in_sizes[1] / 2;
    const int P  = in_sizes[4];

    (void)d_ws; (void)ws_size; (void)n_in; (void)out_size;

    v2f* y  = (v2f*)d_out;
    v2f* y2 = (v2f*)d_out + S;

    const int grid = (S + TILE - 1) / TILE;    // overlap-clamped full blocks
    verblizer_fused_kernel<<<grid, TPB, 0, stream>>>(
        (const v4f*)x, (const v2f*)h, W, b, pu, y, y2, S, P);
}